// Round 1
// baseline (417.045 us; speedup 1.0000x reference)
//
#include <hip/hip_runtime.h>

#define HD 64
#define TT 512
#define BB 256
#define NROWS (BB * TT)  // 131072

// ---------- helpers ----------
__device__ __forceinline__ float rl(float v, int k) {
  return __uint_as_float(__builtin_amdgcn_readlane(__float_as_uint(v), k));
}
__device__ __forceinline__ float wsum(float v) {
#pragma unroll
  for (int m = 32; m >= 1; m >>= 1) v += __shfl_xor(v, m, 64);
  return v;
}
__device__ __forceinline__ float sigmoidf_(float x) {
  return 1.0f / (1.0f + __expf(-x));
}
__device__ __forceinline__ float tanhf_(float x) {
  return 1.0f - 2.0f / (__expf(2.0f * x) + 1.0f);
}
// bf16 (RNE) pack/unpack without hip_bf16 types
__device__ __forceinline__ unsigned short f2bf(float f) {
  unsigned int u = __float_as_uint(f);
  u = (u + 0x7fffu + ((u >> 16) & 1u)) >> 16;
  return (unsigned short)u;
}
__device__ __forceinline__ float ldz(const float* p) { return *p; }
__device__ __forceinline__ float ldz(const unsigned short* p) {
  return __uint_as_float(((unsigned int)(*p)) << 16);
}
__device__ __forceinline__ void store8(float* p, float4 a, float4 b) {
  *(float4*)p = a;
  *(float4*)(p + 4) = b;
}
__device__ __forceinline__ void store8(unsigned short* p, float4 a, float4 b) {
  union { unsigned short us[8]; int4 v; } u;
  u.us[0] = f2bf(a.x); u.us[1] = f2bf(a.y); u.us[2] = f2bf(a.z); u.us[3] = f2bf(a.w);
  u.us[4] = f2bf(b.x); u.us[5] = f2bf(b.y); u.us[6] = f2bf(b.z); u.us[7] = f2bf(b.w);
  *(int4*)p = u.v;
}
__device__ __forceinline__ float4 fma4(float4 a, float s, float4 w) {
  a.x += s * w.x; a.y += s * w.y; a.z += s * w.z; a.w += s * w.w;
  return a;
}
__device__ __forceinline__ float4 add4(float4 a, float4 b) {
  a.x += b.x; a.y += b.y; a.z += b.z; a.w += b.w;
  return a;
}

// ---------- Kernel A: xy = [LN(action@W_act+b_act), relu(...)]; Zx = xy @ W_lstm[0:128] + b_lstm ----------
template <typename ZT>
__global__ __launch_bounds__(256) void kA(const float* __restrict__ act,
                                          const float* __restrict__ Wact,
                                          const float* __restrict__ bact,
                                          const float* __restrict__ g2,
                                          const float* __restrict__ beta2,
                                          const float* __restrict__ Wl,
                                          const float* __restrict__ bl,
                                          ZT* __restrict__ Zx) {
  __shared__ float xy[64][128];
  const int tid = threadIdx.x;
  const int lane = tid & 63;
  const int wv = tid >> 6;
  const int r0blk = blockIdx.x * 64;

  // per-lane W_act column (feature j = lane)
  float wreg[64];
#pragma unroll
  for (int k = 0; k < 64; ++k) wreg[k] = Wact[k * 64 + lane];
  const float ba = bact[lane], gg = g2[lane], bb = beta2[lane];

  // phase 1: wave-per-row, 16 rows per wave
  for (int i = 0; i < 16; ++i) {
    const int r = i * 4 + wv;
    const int row = r0blk + r;
    const float a = act[row * 64 + lane];
    float yd = ba;
#pragma unroll
    for (int k = 0; k < 64; ++k) yd += rl(a, k) * wreg[k];
    const float mu = wsum(yd) * (1.0f / 64.0f);
    const float d = yd - mu;
    const float var = wsum(d * d) * (1.0f / 64.0f);
    const float x = d * rsqrtf(var + 1e-12f) * gg + bb;
    xy[r][lane] = x;
    xy[r][64 + lane] = fmaxf(yd, 0.0f);
  }
  __syncthreads();

  // phase 2: 64x256 tile GEMM, K=128; thread = (tr,tc) micro-tile 8 rows x 8 cols
  const int tc = tid & 31;
  const int tr = tid >> 5;
  const int c0 = tc * 8;
  float4 accA[8], accB[8];
#pragma unroll
  for (int r = 0; r < 8; ++r) {
    accA[r] = make_float4(0.f, 0.f, 0.f, 0.f);
    accB[r] = make_float4(0.f, 0.f, 0.f, 0.f);
  }
  for (int kk = 0; kk < 128; kk += 4) {
    float4 xv[8];
#pragma unroll
    for (int r = 0; r < 8; ++r) xv[r] = *(const float4*)&xy[tr * 8 + r][kk];
#pragma unroll
    for (int dk = 0; dk < 4; ++dk) {
      const float4 wa = *(const float4*)&Wl[(kk + dk) * 256 + c0];
      const float4 wb = *(const float4*)&Wl[(kk + dk) * 256 + c0 + 4];
#pragma unroll
      for (int r = 0; r < 8; ++r) {
        const float xr = (dk == 0) ? xv[r].x : (dk == 1) ? xv[r].y : (dk == 2) ? xv[r].z : xv[r].w;
        accA[r] = fma4(accA[r], xr, wa);
        accB[r] = fma4(accB[r], xr, wb);
      }
    }
  }
  const float4 bla = *(const float4*)&bl[c0];
  const float4 blb = *(const float4*)&bl[c0 + 4];
#pragma unroll
  for (int r = 0; r < 8; ++r) {
    const int row = r0blk + tr * 8 + r;
    store8(&Zx[(size_t)row * 256 + c0], add4(accA[r], bla), add4(accB[r], blb));
  }
}

// ---------- Kernel B: LSTM scan, one block per batch element ----------
template <typename ZT>
__global__ __launch_bounds__(256) void kB(const ZT* __restrict__ Zx,
                                          const float* __restrict__ Wl,
                                          const float* __restrict__ c0p,
                                          const float* __restrict__ h0p,
                                          float* __restrict__ hs,
                                          float* __restrict__ cfin,
                                          float* __restrict__ hfin) {
  __shared__ float zbuf[2][256];
  const int tid = threadIdx.x;
  const int m = tid & 63;
  const int b = blockIdx.x;

  // W_h column for this thread's output column (64 VGPRs)
  float wcol[64];
#pragma unroll
  for (int k = 0; k < 64; ++k) wcol[k] = Wl[(128 + k) * 256 + tid];

  float c = c0p[b * 64 + m];
  float h = h0p[b * 64 + m];

  const ZT* zrow = Zx + (size_t)b * TT * 256;
  float* hsrow = hs + (size_t)b * TT * 64;

  // prefetch depth 4
  float p0 = ldz(&zrow[0 * 256 + tid]);
  float p1 = ldz(&zrow[1 * 256 + tid]);
  float p2 = ldz(&zrow[2 * 256 + tid]);
  float p3 = ldz(&zrow[3 * 256 + tid]);

#define STEP(PZ, T)                                                        \
  {                                                                        \
    float a0 = 0.f, a1 = 0.f, a2 = 0.f, a3 = 0.f;                          \
    _Pragma("unroll") for (int k = 0; k < 64; k += 4) {                    \
      a0 += rl(h, k) * wcol[k];                                            \
      a1 += rl(h, k + 1) * wcol[k + 1];                                    \
      a2 += rl(h, k + 2) * wcol[k + 2];                                    \
      a3 += rl(h, k + 3) * wcol[k + 3];                                    \
    }                                                                      \
    const float zv = PZ + ((a0 + a1) + (a2 + a3));                         \
    zbuf[(T)&1][tid] = zv;                                                 \
    int tn = (T) + 4;                                                      \
    if (tn > TT - 1) tn = TT - 1;                                          \
    PZ = ldz(&zrow[(size_t)tn * 256 + tid]);                               \
    asm volatile("s_waitcnt lgkmcnt(0)\n\ts_barrier" ::: "memory");        \
    const float zi = zbuf[(T)&1][m];                                       \
    const float zj = zbuf[(T)&1][64 + m];                                  \
    const float zf = zbuf[(T)&1][128 + m];                                 \
    const float zo = zbuf[(T)&1][192 + m];                                 \
    c = c * sigmoidf_(zf + 1.0f) + sigmoidf_(zi) * tanhf_(zj);             \
    h = sigmoidf_(zo) * tanhf_(c);                                         \
    if (tid < 64) hsrow[(T)*64 + m] = h;                                   \
  }

  for (int t = 0; t < TT; t += 4) {
    STEP(p0, t)
    STEP(p1, t + 1)
    STEP(p2, t + 2)
    STEP(p3, t + 3)
  }
#undef STEP

  if (tid < 64) {
    cfin[b * 64 + m] = c;
    hfin[b * 64 + m] = h;
  }
}

// ---------- Kernel C: out = LN(hs) ; q = out @ W_out + b_out ----------
__global__ __launch_bounds__(256) void kC(const float* __restrict__ hs,
                                          const float* __restrict__ g3,
                                          const float* __restrict__ beta3,
                                          const float* __restrict__ Wout,
                                          const float* __restrict__ bout,
                                          float* __restrict__ q) {
  const int lane = threadIdx.x & 63;
  const int wv = threadIdx.x >> 6;
  const float g = g3[lane], be = beta3[lane], wo = Wout[lane], bo = bout[0];
  for (int n = blockIdx.x * 4 + wv; n < NROWS; n += gridDim.x * 4) {
    const float v = hs[(size_t)n * 64 + lane];
    const float mu = wsum(v) * (1.0f / 64.0f);
    const float d = v - mu;
    const float var = wsum(d * d) * (1.0f / 64.0f);
    const float xn = d * rsqrtf(var + 1e-12f) * g + be;
    const float s = wsum(xn * wo);
    if (lane == 0) q[n] = s + bo;
  }
}

// ---------- launch ----------
extern "C" void kernel_launch(void* const* d_in, const int* in_sizes, int n_in,
                              void* d_out, int out_size, void* d_ws, size_t ws_size,
                              hipStream_t stream) {
  const float* action = (const float*)d_in[1];
  const float* c0 = (const float*)d_in[2];
  const float* h0 = (const float*)d_in[3];
  const float* Wact = (const float*)d_in[8];
  const float* bact = (const float*)d_in[9];
  const float* g2 = (const float*)d_in[10];
  const float* b2 = (const float*)d_in[11];
  const float* Wl = (const float*)d_in[12];
  const float* bl = (const float*)d_in[13];
  const float* g3 = (const float*)d_in[14];
  const float* b3 = (const float*)d_in[15];
  const float* Wout = (const float*)d_in[16];
  const float* bout = (const float*)d_in[17];

  float* q = (float*)d_out;
  float* cfin = q + NROWS;
  float* hfin = cfin + BB * HD;

  const size_t zx32 = (size_t)NROWS * 256 * sizeof(float);
  const size_t zx16 = (size_t)NROWS * 256 * sizeof(unsigned short);
  const size_t hsb = (size_t)NROWS * 64 * sizeof(float);

  if (ws_size >= zx32 + hsb) {
    float* Zx = (float*)d_ws;
    float* hs = (float*)((char*)d_ws + zx32);
    kA<float><<<NROWS / 64, 256, 0, stream>>>(action, Wact, bact, g2, b2, Wl, bl, Zx);
    kB<float><<<BB, 256, 0, stream>>>(Zx, Wl, c0, h0, hs, cfin, hfin);
    kC<<<2048, 256, 0, stream>>>(hs, g3, b3, Wout, bout, q);
  } else {
    unsigned short* Zx = (unsigned short*)d_ws;
    float* hs = (float*)((char*)d_ws + zx16);
    kA<unsigned short><<<NROWS / 64, 256, 0, stream>>>(action, Wact, bact, g2, b2, Wl, bl, Zx);
    kB<unsigned short><<<BB, 256, 0, stream>>>(Zx, Wl, c0, h0, hs, cfin, hfin);
    kC<<<2048, 256, 0, stream>>>(hs, g3, b3, Wout, bout, q);
  }
}